// Round 1
// baseline (103.253 us; speedup 1.0000x reference)
//
#include <hip/hip_runtime.h>

#define R 192
#define BATCH 1024
#define TILE 16
#define NT (R / TILE)   // 12 tiles per dimension

// ws[0]=sum (pos-tpos)^2, ws[1]=sum (size-tsize)^2, ws[2]=sum overlap, ws[3]=sum adj dist
__global__ void init_ws_kernel(float* __restrict__ ws) {
    int t = threadIdx.x;
    if (t < 4) ws[t] = 0.0f;
}

__global__ __launch_bounds__(256) void floorplan_main_kernel(
    const float* __restrict__ pos,    // [B,R,2]
    const float* __restrict__ siz,    // [B,R,2]
    const float* __restrict__ tpos,   // [B,R,2]
    const float* __restrict__ tsiz,   // [B,R,2]
    const int*   __restrict__ adj,    // [R,R] (batch 0)
    float* __restrict__ ws)
{
    __shared__ float sx[R], sy[R], sw[R], sh[R];
    __shared__ float wsum[4][4];

    const int b   = blockIdx.x;
    const int tid = threadIdx.x;

    const float* pb  = pos  + (size_t)b * (R * 2);
    const float* sb  = siz  + (size_t)b * (R * 2);
    const float* tpb = tpos + (size_t)b * (R * 2);
    const float* tsb = tsiz + (size_t)b * (R * 2);

    float mse_p = 0.0f, mse_s = 0.0f;

    // Stage into LDS + fused MSE partials. R*2 = 384 elements, 256 threads.
    for (int idx = tid; idx < R * 2; idx += 256) {
        float p  = pb[idx];
        float s  = sb[idx];
        float dp = p - tpb[idx];
        float ds = s - tsb[idx];
        mse_p += dp * dp;
        mse_s += ds * ds;
        int r = idx >> 1;
        if (idx & 1) { sy[r] = p; sh[r] = s; }
        else         { sx[r] = p; sw[r] = s; }
    }
    __syncthreads();

    // Pairwise loop over upper-triangular 16x16 tiles.
    float ov = 0.0f, ad = 0.0f;
    const int li = tid >> 4;    // 0..15 : i within tile
    const int lj = tid & 15;    // 0..15 : j within tile

    for (int ti = 0; ti < NT; ++ti) {
        const int   i   = ti * TILE + li;
        const float xi  = sx[i], yi = sy[i], wi = sw[i], hi = sh[i];
        const float xiw = xi + wi;
        const float yih = yi + hi;
        const float cxi = xi + 0.5f * wi;
        const float cyi = yi + 0.5f * hi;

        for (int tj = ti; tj < NT; ++tj) {
            const int j = tj * TILE + lj;
            if (i < j) {
                const float xj = sx[j], yj = sy[j], wj = sw[j], hj = sh[j];
                float ow = fminf(xiw, xj + wj) - fmaxf(xi, xj);
                float oh = fminf(yih, yj + hj) - fmaxf(yi, yj);
                ow = fmaxf(ow, 0.0f);
                oh = fmaxf(oh, 0.0f);
                ov += ow * oh;
                if (adj[i * R + j] > 0) {
                    float dx = cxi - (xj + 0.5f * wj);
                    float dy = cyi - (yj + 0.5f * hj);
                    ad += sqrtf(dx * dx + dy * dy);
                }
            }
        }
    }

    // Reduce 4 accumulators: 64-lane shuffle, then cross-wave via LDS.
    for (int off = 32; off > 0; off >>= 1) {
        mse_p += __shfl_down(mse_p, off);
        mse_s += __shfl_down(mse_s, off);
        ov    += __shfl_down(ov, off);
        ad    += __shfl_down(ad, off);
    }
    const int wid  = tid >> 6;
    const int lane = tid & 63;
    if (lane == 0) {
        wsum[wid][0] = mse_p;
        wsum[wid][1] = mse_s;
        wsum[wid][2] = ov;
        wsum[wid][3] = ad;
    }
    __syncthreads();
    if (tid < 4) {
        float v = wsum[0][tid] + wsum[1][tid] + wsum[2][tid] + wsum[3][tid];
        atomicAdd(&ws[tid], v);
    }
}

__global__ void finalize_kernel(const float* __restrict__ ws, float* __restrict__ out) {
    if (threadIdx.x == 0 && blockIdx.x == 0) {
        const float invN = 1.0f / (float)(BATCH * R * 2);
        const float invB = 1.0f / (float)BATCH;
        float pos_loss  = ws[0] * invN;
        float size_loss = ws[1] * invN;
        float overlap   = ws[2] * invB;
        float adjl      = ws[3] * invB;
        out[0] = pos_loss + size_loss + 0.5f * overlap + 0.3f * adjl;
        out[1] = pos_loss;
        out[2] = size_loss;
        out[3] = overlap;
        out[4] = adjl;
    }
}

extern "C" void kernel_launch(void* const* d_in, const int* in_sizes, int n_in,
                              void* d_out, int out_size, void* d_ws, size_t ws_size,
                              hipStream_t stream) {
    const float* pos  = (const float*)d_in[0];
    const float* siz  = (const float*)d_in[1];
    const float* tpos = (const float*)d_in[2];
    const float* tsiz = (const float*)d_in[3];
    const int*   adj  = (const int*)d_in[4];
    float* ws  = (float*)d_ws;
    float* out = (float*)d_out;

    hipLaunchKernelGGL(init_ws_kernel, dim3(1), dim3(64), 0, stream, ws);
    hipLaunchKernelGGL(floorplan_main_kernel, dim3(BATCH), dim3(256), 0, stream,
                       pos, siz, tpos, tsiz, adj, ws);
    hipLaunchKernelGGL(finalize_kernel, dim3(1), dim3(1), 0, stream, ws, out);
}

// Round 2
// 101.070 us; speedup vs baseline: 1.0216x; 1.0216x over previous
//
#include <hip/hip_runtime.h>

#define R 192
#define BATCH 1024
#define TILE 16
#define NT (R / TILE)   // 12 tiles per dimension
#define NBITWORDS (R * 6)  // 192 rows x 6 uint32 (192 bits) per row

// ws layout: ws[0..3] = float accumulators (pos_mse, size_mse, overlap, adj)
//            ws+16 bytes ... : uint32 adjacency bitmask [R][6], triu-baked (bit j set iff j>i && adj[i][j]>0)

// Build bitmask with one ballot per 64 elements; also zero the 4 accumulators.
__global__ __launch_bounds__(256) void build_mask_kernel(
    const int* __restrict__ adj, float* __restrict__ ws)
{
    unsigned int* wsbits = (unsigned int*)(ws + 4);
    const int e = blockIdx.x * 256 + threadIdx.x;   // 0 .. R*R-1
    if (e < 4) ws[e] = 0.0f;
    if (e >= R * R) return;
    const int i = e / R;
    const int j = e - i * R;
    const bool pred = (adj[e] > 0) && (j > i);
    const unsigned long long m = __ballot(pred);
    const int lane = e & 63;
    if (lane == 0)  wsbits[e >> 5] = (unsigned int)m;
    if (lane == 32) wsbits[e >> 5] = (unsigned int)(m >> 32);
}

__global__ __launch_bounds__(256) void floorplan_main_kernel(
    const float* __restrict__ pos,    // [B,R,2]
    const float* __restrict__ siz,    // [B,R,2]
    const float* __restrict__ tpos,   // [B,R,2]
    const float* __restrict__ tsiz,   // [B,R,2]
    float* __restrict__ ws)
{
    __shared__ float4 room[R];            // x,y,w,h
    __shared__ unsigned int sadj[NBITWORDS];
    __shared__ float wsum[4][4];

    const int b   = blockIdx.x;
    const int sel = blockIdx.y;           // 0/1 : tj-stripe parity
    const int tid = threadIdx.x;

    const float2* pb  = (const float2*)(pos  + (size_t)b * (R * 2));
    const float2* sb  = (const float2*)(siz  + (size_t)b * (R * 2));
    const float2* tpb = (const float2*)(tpos + (size_t)b * (R * 2));
    const float2* tsb = (const float2*)(tsiz + (size_t)b * (R * 2));
    const unsigned int* wsbits = (const unsigned int*)(ws + 4);

    float mse_p = 0.0f, mse_s = 0.0f;

    // Stage rooms into LDS as float4 + fused MSE partials (threads 0..191).
    if (tid < R) {
        float2 p  = pb[tid];
        float2 s  = sb[tid];
        float2 tp = tpb[tid];
        float2 ts = tsb[tid];
        float dpx = p.x - tp.x, dpy = p.y - tp.y;
        float dsx = s.x - ts.x, dsy = s.y - ts.y;
        mse_p = dpx * dpx + dpy * dpy;
        mse_s = dsx * dsx + dsy * dsy;
        room[tid] = make_float4(p.x, p.y, s.x, s.y);
    }
    // Stage adjacency bitmask (1152 words / 256 threads).
    for (int w = tid; w < NBITWORDS; w += 256) sadj[w] = wsbits[w];
    __syncthreads();

    // Only one stripe contributes the MSE terms.
    if (sel != 0) { mse_p = 0.0f; mse_s = 0.0f; }

    float ov = 0.0f, ad = 0.0f;
    const int li = tid >> 4;    // 0..15 : i within tile
    const int lj = tid & 15;    // 0..15 : j within tile

    for (int ti = 0; ti < NT; ++ti) {
        const int   i  = ti * TILE + li;
        const float4 ri = room[i];
        const float xi  = ri.x, yi = ri.y;
        const float xiw = ri.x + ri.z;
        const float yih = ri.y + ri.w;
        const float cxi = fmaf(0.5f, ri.z, ri.x);
        const float cyi = fmaf(0.5f, ri.w, ri.y);
        const unsigned int* rowbits = &sadj[i * 6];

        for (int tj = ti + sel; tj < NT; tj += 2) {
            const int j = tj * TILE + lj;
            const float4 rj = room[j];
            float ow = fminf(xiw, rj.x + rj.z) - fmaxf(xi, rj.x);
            float oh = fminf(yih, rj.y + rj.w) - fmaxf(yi, rj.y);
            ow = fmaxf(ow, 0.0f);
            oh = fmaxf(oh, 0.0f);
            float area = ow * oh;
            ov += (i < j) ? area : 0.0f;            // only diagonal tiles have i>=j lanes

            unsigned int wbits = rowbits[tj >> 1];  // 16 bits per (tj parity)
            unsigned int bit = (wbits >> (((tj & 1) << 4) + lj)) & 1u;
            float dx = cxi - fmaf(0.5f, rj.z, rj.x);
            float dy = cyi - fmaf(0.5f, rj.w, rj.y);
            float sq = fmaf(dx, dx, dy * dy);
            float d  = __builtin_amdgcn_sqrtf(sq);
            ad += bit ? d : 0.0f;                   // triu baked into bitmask
        }
    }

    // Reduce 4 accumulators: 64-lane shuffle, then cross-wave via LDS.
    for (int off = 32; off > 0; off >>= 1) {
        mse_p += __shfl_down(mse_p, off);
        mse_s += __shfl_down(mse_s, off);
        ov    += __shfl_down(ov, off);
        ad    += __shfl_down(ad, off);
    }
    const int wid  = tid >> 6;
    const int lane = tid & 63;
    if (lane == 0) {
        wsum[wid][0] = mse_p;
        wsum[wid][1] = mse_s;
        wsum[wid][2] = ov;
        wsum[wid][3] = ad;
    }
    __syncthreads();
    if (tid < 4) {
        float v = wsum[0][tid] + wsum[1][tid] + wsum[2][tid] + wsum[3][tid];
        atomicAdd(&ws[tid], v);
    }
}

__global__ void finalize_kernel(const float* __restrict__ ws, float* __restrict__ out) {
    if (threadIdx.x == 0 && blockIdx.x == 0) {
        const float invN = 1.0f / (float)(BATCH * R * 2);
        const float invB = 1.0f / (float)BATCH;
        float pos_loss  = ws[0] * invN;
        float size_loss = ws[1] * invN;
        float overlap   = ws[2] * invB;
        float adjl      = ws[3] * invB;
        out[0] = pos_loss + size_loss + 0.5f * overlap + 0.3f * adjl;
        out[1] = pos_loss;
        out[2] = size_loss;
        out[3] = overlap;
        out[4] = adjl;
    }
}

extern "C" void kernel_launch(void* const* d_in, const int* in_sizes, int n_in,
                              void* d_out, int out_size, void* d_ws, size_t ws_size,
                              hipStream_t stream) {
    const float* pos  = (const float*)d_in[0];
    const float* siz  = (const float*)d_in[1];
    const float* tpos = (const float*)d_in[2];
    const float* tsiz = (const float*)d_in[3];
    const int*   adj  = (const int*)d_in[4];
    float* ws  = (float*)d_ws;
    float* out = (float*)d_out;

    hipLaunchKernelGGL(build_mask_kernel, dim3((R * R + 255) / 256), dim3(256), 0, stream,
                       adj, ws);
    hipLaunchKernelGGL(floorplan_main_kernel, dim3(BATCH, 2), dim3(256), 0, stream,
                       pos, siz, tpos, tsiz, ws);
    hipLaunchKernelGGL(finalize_kernel, dim3(1), dim3(1), 0, stream, ws, out);
}